// Round 14
// baseline (118.861 us; speedup 1.0000x reference)
//
#include <hip/hip_runtime.h>
#include <math.h>

#define Bb   48
#define Ww   100
#define Nn   1000
#define EMB  128
#define Hh   8
#define LL   101     // depot + 100 neighbors
#define LOCALK 100
#define TPB  128
#define PPB  2       // problems (waves) per block in kernel A

typedef float f4v __attribute__((ext_vector_type(4)));

// ---- workspace layout (float offsets)
#define WS_A     0       // [8][128]  a_h = (Wk q_h)/4
#define WS_PE    1024    // [101][128] pos-enc f32
#define WS_AC    13952   // [3][8] A_i[h] then [8] C[h]
#define WS_WVI   13984   // [4][128]  w_i·Wv[:,hd] (i=3 -> b)
#define WS_PEA   14496   // [8][101]  pe[l]·a_h
#define WS_PVT   15304   // f16 [101][128]  PVT[l][hd] = pe[l]·Wv[:,hd]
#define WS_GPT   21768   // f16 [128][104]  GPT[hd][l] = Wcw[hd]·pe[l], l>=101 -> 0
#define WS_WCW   28424   // f32 [4][128]  Wcw·w_i  (i=3 -> b)
#define WS_CB    28936   // f32 [4]       Wcb·w_i
#define WS_CBPE  28940   // f32 [104]     Wcb·pe[l]
// end 29044 floats = 116 KB

// ---- kernel A per-problem LDS arena (bytes), regions time-multiplexed
#define AR_SIZE 7360
#define AR_LIST 4288     // u64[100]
#define AR_SEL  5088     // i32[104]  (node | 0x4000 inf-flag; pad 101..103 = 0)
#define AR_PERM 5504     // u8[104]
#define AR_SMK  5616     // f32[101]
#define AR_F3   6032     // f32[304]  (pad [303] = 0)
#define AR_COEF 7248     // f32[24]

// staging layout inside each out row (f32 slots):
//  [0..415]   attn f16[8][104]
//  [416..567] feat f16[304]
//  [568..619] sel  u16[104]
//  [620..643] coef f32[24]

#define WSYNC() do { __builtin_amdgcn_wave_barrier(); asm volatile("" ::: "memory"); } while (0)

__device__ __forceinline__ unsigned f2key(float x) {
    unsigned u = __float_as_uint(x);
    return (u & 0x80000000u) ? ~u : (u | 0x80000000u);
}
__device__ __forceinline__ float key2f(unsigned k) {
    unsigned u = (k & 0x80000000u) ? (k & 0x7fffffffu) : ~k;
    return __uint_as_float(u);
}
__device__ __forceinline__ unsigned short f2hbits(float x) {
    union { _Float16 h; unsigned short u; } cv;
    cv.h = (_Float16)x;
    return cv.u;
}

// ---- S1: q, a, A/C (block 0); pe + WVi (blocks 1..)
__global__ void setup1(const float* __restrict__ cur, const float* __restrict__ Wq,
                       const float* __restrict__ Wk, const float* __restrict__ iw,
                       const float* __restrict__ ib, const float* __restrict__ Wv,
                       float* __restrict__ ws) {
    const int t = threadIdx.x, b = blockIdx.x;
    if (b == 0) {
        __shared__ float qs[EMB];
        __shared__ float as_[Hh * EMB];
        if (t < EMB) {
            float acc = 0.f;
            for (int e = 0; e < EMB; ++e) acc += cur[e] * Wq[e * EMB + t];
            qs[t] = acc;
        }
        __syncthreads();
        for (int i = t; i < Hh * EMB; i += 256) {
            int h = i >> 7, e = i & 127;
            float acc = 0.f;
            for (int d = 0; d < 16; ++d) acc += Wk[e * EMB + h * 16 + d] * qs[h * 16 + d];
            acc *= 0.25f;
            as_[i] = acc; ws[WS_A + i] = acc;
        }
        __syncthreads();
        if (t < 32) {
            int i = t >> 3, h = t & 7;
            const float* src = (i == 0) ? iw : (i == 1) ? iw + EMB : (i == 2) ? iw + 2 * EMB : ib;
            float acc = 0.f;
            for (int e = 0; e < EMB; ++e) acc += src[e] * as_[h * EMB + e];
            ws[WS_AC + t] = acc;
        }
    } else {
        int base = (b - 1) * 256 + t;
        const float kneg = -0.14619587891040738f;  // -ln(10000)/63
        if (base < LL * EMB) {
            int l = base >> 7, c = base & 127, ic = c & 63;
            float inv = expf((float)ic * kneg);
            float v = (float)l * inv;
            ws[WS_PE + base] = (c < 64) ? sinf(v) : cosf(v);
        } else if (base < LL * EMB + 512) {
            int j = base - LL * EMB;
            int iv = j >> 7, hd = j & 127;
            const float* src = (iv == 0) ? iw : (iv == 1) ? iw + EMB : (iv == 2) ? iw + 2 * EMB : ib;
            float acc = 0.f;
            for (int e = 0; e < EMB; ++e) acc += src[e] * Wv[e * EMB + hd];
            ws[WS_WVI + j] = acc;
        }
    }
}

// ---- S2: PVT f16, GPT f16, PEA, WCW, cb, cbpe  (reads ws PE/A from setup1)
__global__ void setup2(const float* __restrict__ Wv, const float* __restrict__ Wcw,
                       const float* __restrict__ Wcb, const float* __restrict__ iw,
                       const float* __restrict__ ib, float* __restrict__ ws) {
    int idx = blockIdx.x * 256 + threadIdx.x;
    if (idx < 12928) {                               // PVT[l][hd]
        int l = idx >> 7, hd = idx & 127;
        const float* pr = ws + WS_PE + l * EMB;
        float acc = 0.f;
        for (int e = 0; e < EMB; ++e) acc += pr[e] * Wv[e * EMB + hd];
        ((_Float16*)(ws + WS_PVT))[idx] = (_Float16)acc;
    } else if (idx < 12928 + 13312) {                // GPT[hd][l]
        int j = idx - 12928;
        int hd = j / 104, l = j - hd * 104;
        float acc = 0.f;
        if (l < LL) {
            const float* wr = Wcw + hd * EMB;
            const float* pr = ws + WS_PE + l * EMB;
            for (int e = 0; e < EMB; ++e) acc += wr[e] * pr[e];
        }
        ((_Float16*)(ws + WS_GPT))[j] = (_Float16)acc;
    } else if (idx < 26240 + 808) {                  // PEA[h][l]
        int j = idx - 26240;
        int h = j / LL, l = j - h * LL;
        const float* pr = ws + WS_PE + l * EMB;
        const float* ar = ws + WS_A + h * EMB;
        float acc = 0.f;
        for (int e = 0; e < EMB; ++e) acc += pr[e] * ar[e];
        ws[WS_PEA + j] = acc;
    } else if (idx < 27048 + 512) {                  // WCW[i][hd]
        int j = idx - 27048;
        int i = j >> 7, hd = j & 127;
        const float* src = (i == 0) ? iw : (i == 1) ? iw + EMB : (i == 2) ? iw + 2 * EMB : ib;
        const float* wr = Wcw + hd * EMB;
        float acc = 0.f;
        for (int e = 0; e < EMB; ++e) acc += wr[e] * src[e];
        ws[WS_WCW + j] = acc;
    } else if (idx < 27560 + 4) {                    // cb[i]
        int i = idx - 27560;
        const float* src = (i == 0) ? iw : (i == 1) ? iw + EMB : (i == 2) ? iw + 2 * EMB : ib;
        float acc = 0.f;
        for (int e = 0; e < EMB; ++e) acc += Wcb[e] * src[e];
        ws[WS_CB + i] = acc;
    } else if (idx < 27564 + 104) {                  // cbpe[l]
        int l = idx - 27564;
        float acc = 0.f;
        if (l < LL) {
            const float* pr = ws + WS_PE + l * EMB;
            for (int e = 0; e < EMB; ++e) acc += Wcb[e] * pr[e];
        }
        ws[WS_CBPE + l] = acc;
    }
}

// ================= Kernel A: select + features + attn + coef -> staging =================
__global__ __launch_bounds__(TPB, 6) void kernelA(
    const float* __restrict__ dist,
    const float* __restrict__ xy,
    const float* __restrict__ ndem,
    const float* __restrict__ ninf,
    const float* __restrict__ ws,
    float* __restrict__ out) {

    __shared__ __align__(16) char smem[PPB][AR_SIZE];
    __shared__ __align__(16) float sPEA[Hh * LL + 32];

    const int tid  = threadIdx.x;
    const int w    = tid >> 6;
    const int lane = tid & 63;
    const int bid  = blockIdx.x;
    const int bw   = ((bid & 7) * 300 + (bid >> 3)) * PPB + w;   // XCD-bijective

    char* A = smem[w];
    int*                hist4 = (int*)A;                      // [4][260]
    _Float16*           attnh = (_Float16*)A;                 // [8][104] (after select)
    unsigned long long* list  = (unsigned long long*)(A + AR_LIST);
    int*                sel   = (int*)(A + AR_SEL);
    unsigned char*      perm  = (unsigned char*)(A + AR_PERM);
    float*              smk   = (float*)(A + AR_SMK);
    float*              feat3 = (float*)(A + AR_F3);
    float*              coefA = (float*)(A + AR_COEF);

    const float* distRow = dist + (size_t)bw * Nn;
    const float* maskRow = ninf + (size_t)bw * Nn;
    const float* xyRow   = xy   + (size_t)bw * Nn * 2;
    const float* demRow  = ndem + (size_t)bw * Nn;

    // ---- phase 0: issue ALL FOUR input streams at once (single latency exposure)
    float dvf[16], mkf[16];
    float xs[16], ys[16], dd[16];
    {
        float4 dv[4], mv[4], a0[4], a1[4], d0[4];
        #pragma unroll
        for (int c = 0; c < 4; ++c) {
            int n0 = c * 256 + lane * 4;
            if (n0 < Nn) {
                dv[c] = *(const float4*)(distRow + n0);
                mv[c] = *(const float4*)(maskRow + n0);
                a0[c] = *(const float4*)(xyRow + 2 * n0);
                a1[c] = *(const float4*)(xyRow + 2 * n0 + 4);
                d0[c] = *(const float4*)(demRow + n0);
            } else {
                dv[c] = mv[c] = a0[c] = a1[c] = d0[c] = make_float4(0.f, 0.f, 0.f, 0.f);
            }
        }
        // zero sub-histograms while loads are in flight
        #pragma unroll
        for (int k = 0; k < 5; ++k) {
            int idx = lane + 64 * k;
            if (idx < 260) ((int4*)hist4)[idx] = make_int4(0, 0, 0, 0);
        }
        // stage PEA+AC to block LDS while loads are in flight
        for (int i = tid; i < Hh * LL + 32; i += TPB)
            sPEA[i] = (i < Hh * LL) ? ws[WS_PEA + i] : ws[WS_AC + (i - Hh * LL)];
        #pragma unroll
        for (int c = 0; c < 4; ++c) {
            dvf[4*c+0] = dv[c].x; dvf[4*c+1] = dv[c].y; dvf[4*c+2] = dv[c].z; dvf[4*c+3] = dv[c].w;
            mkf[4*c+0] = mv[c].x; mkf[4*c+1] = mv[c].y; mkf[4*c+2] = mv[c].z; mkf[4*c+3] = mv[c].w;
            xs[4*c+0] = a0[c].x; ys[4*c+0] = a0[c].y;
            xs[4*c+1] = a0[c].z; ys[4*c+1] = a0[c].w;
            xs[4*c+2] = a1[c].x; ys[4*c+2] = a1[c].y;
            xs[4*c+3] = a1[c].z; ys[4*c+3] = a1[c].w;
            dd[4*c+0] = d0[c].x; dd[4*c+1] = d0[c].y; dd[4*c+2] = d0[c].z; dd[4*c+3] = d0[c].w;
        }
    }
    __syncthreads();   // sPEA visible to both waves
    const float* sAC = sPEA + Hh * LL;

    unsigned long long rk[16];
    #pragma unroll
    for (int r = 0; r < 16; ++r) {
        int n = (r >> 2) * 256 + lane * 4 + (r & 3);
        unsigned long long kv = ~0ull;
        if (n >= 1 && n < Nn) {
            float de = dvf[r] - mkf[r];
            kv = ((unsigned long long)f2key(de) << 32) | (unsigned)n;
        }
        rk[r] = kv;
    }
    WSYNC();

    // ---- radix select (MSB-first, 4 bank-staggered sub-hists), wave-local
    unsigned long long prefix = 0;
    int shift = 56;
    int remRank = 99;
    const unsigned long long ltm = (1ull << lane) - 1ull;
    const int g0 = (lane >> 4) * 260;
    for (int round = 0; round < 8; ++round) {
        shift = 56 - 8 * round;
        #pragma unroll
        for (int r = 0; r < 16; ++r) {
            unsigned long long kv = rk[r];
            bool in = (kv != ~0ull) &&
                      (round == 0 || (kv >> (shift + 8)) == (prefix >> (shift + 8)));
            if (in) atomicAdd(&hist4[g0 + (int)((kv >> shift) & 0xffull)], 1);
        }
        WSYNC();
        int4 h0 = *(int4*)&hist4[0 * 260 + 4 * lane];
        int4 h1 = *(int4*)&hist4[1 * 260 + 4 * lane];
        int4 h2 = *(int4*)&hist4[2 * 260 + 4 * lane];
        int4 h3 = *(int4*)&hist4[3 * 260 + 4 * lane];
        int4 z = make_int4(0, 0, 0, 0);
        *(int4*)&hist4[0 * 260 + 4 * lane] = z;
        *(int4*)&hist4[1 * 260 + 4 * lane] = z;
        *(int4*)&hist4[2 * 260 + 4 * lane] = z;
        *(int4*)&hist4[3 * 260 + 4 * lane] = z;
        int cx = h0.x + h1.x + h2.x + h3.x;
        int cy = h0.y + h1.y + h2.y + h3.y;
        int cz = h0.z + h1.z + h2.z + h3.z;
        int cw = h0.w + h1.w + h2.w + h3.w;
        int s = cx + cy + cz + cw;
        int incl = s;
        #pragma unroll
        for (int o = 1; o < 64; o <<= 1) { int t = __shfl_up(incl, o, 64); if (lane >= o) incl += t; }
        int e0 = incl - s;
        int e1 = e0 + cx, e2 = e1 + cy, e3 = e2 + cz;
        int bc = -1, ec = 0, cc = 0;
        if (cx > 0 && remRank >= e0 && remRank < e1)      { bc = 4*lane+0; ec = e0; cc = cx; }
        if (cy > 0 && remRank >= e1 && remRank < e2)      { bc = 4*lane+1; ec = e1; cc = cy; }
        if (cz > 0 && remRank >= e2 && remRank < e3)      { bc = 4*lane+2; ec = e2; cc = cz; }
        if (cw > 0 && remRank >= e3 && remRank < e3 + cw) { bc = 4*lane+3; ec = e3; cc = cw; }
        unsigned long long fm = __ballot(bc >= 0);
        int srcl = __ffsll((unsigned long long)fm) - 1;
        bc = __shfl(bc, srcl, 64); ec = __shfl(ec, srcl, 64); cc = __shfl(cc, srcl, 64);
        prefix |= ((unsigned long long)(unsigned)bc) << shift;
        remRank -= ec;
        if (cc == 1) break;
    }
    unsigned long long pk = 0; bool pf = false;
    #pragma unroll
    for (int r = 0; r < 16; ++r)
        if ((rk[r] >> shift) == (prefix >> shift)) { pk = rk[r]; pf = true; }
    {
        unsigned long long fm = __ballot(pf);
        int srcl = __ffsll((unsigned long long)fm) - 1;
        pk = __shfl(pk, srcl, 64);
    }
    const unsigned long long pivot = pk;

    // ---- ballot-compact the 100 keys <= pivot into list (p-order)
    int cnt_run = 0;
    #pragma unroll
    for (int r = 0; r < 16; ++r) {
        bool p = rk[r] <= pivot;
        unsigned long long m = __ballot(p);
        if (p) list[cnt_run + (int)__popcll(m & ltm)] = rk[r];
        cnt_run += (int)__popcll(m);
    }
    WSYNC();

    // ---- parallel rank: perm[p] = rank+1 ; norm max
    {
        unsigned long long kv0 = list[lane];
        const bool has1 = lane < (LOCALK - 64);
        unsigned long long kv1 = has1 ? list[lane + 64] : ~0ull;
        int r0 = 0, r1 = 0;
        #pragma unroll 4
        for (int j = 0; j < LOCALK; ++j) {
            unsigned long long lv = list[j];
            r0 += (lv < kv0);
            r1 += (lv < kv1);
        }
        float v0 = key2f((unsigned)(kv0 >> 32));
        float dvm = isinf(v0) ? 0.f : v0;
        perm[lane] = (unsigned char)(r0 + 1);
        if (has1) {
            float v1 = key2f((unsigned)(kv1 >> 32));
            perm[lane + 64] = (unsigned char)(r1 + 1);
            dvm = fmaxf(dvm, isinf(v1) ? 0.f : v1);
        }
        #pragma unroll
        for (int o = 32; o > 0; o >>= 1) dvm = fmaxf(dvm, __shfl_xor(dvm, o, 64));
        const float nmax = dvm;
        const bool  norm_on = (nmax != 0.f);
        const float nfac = nmax + 1e-6f;
        WSYNC();

        // ---- scatter features from registers (no global gather)
        int crun = 0;
        #pragma unroll
        for (int r = 0; r < 16; ++r) {
            unsigned long long kv = rk[r];
            bool p = kv <= pivot;
            unsigned long long m = __ballot(p);
            int pos = crun + (int)__popcll(m & ltm);
            crun += (int)__popcll(m);
            if (p) {
                int rnk = perm[pos];
                float val = key2f((unsigned)(kv >> 32));
                bool infm = isinf(val);
                float fx = infm ? 0.f : xs[r];
                float fy = infm ? 0.f : ys[r];
                float fd = infm ? 0.f : dd[r];
                if (norm_on) { fx /= nfac; fy /= nfac; }
                int n = (int)(kv & 0xffffffu);
                feat3[rnk] = fx; feat3[101 + rnk] = fy; feat3[202 + rnk] = fd;
                smk[rnk] = mkf[r];
                sel[rnk] = n | (infm ? 0x4000 : 0);
            }
        }
        if (lane == 0) {
            feat3[0] = 0.f; feat3[101] = 0.f; feat3[202] = 0.f; feat3[303] = 0.f;
            smk[0] = mkf[0];
            sel[0] = 0x4000;
            sel[101] = 0; sel[102] = 0; sel[103] = 0;
        }
    }
    WSYNC();

    // ---- fused scores + softmax + coef: 8 lanes per head
    const int h = lane >> 3, ln8 = lane & 7;
    {
        const float A0 = sAC[h], A1 = sAC[8 + h], A2 = sAC[16 + h], Cc = sAC[24 + h];
        const float* pea = sPEA + h * LL;
        float ev[13];
        float mx = -INFINITY;
        #pragma unroll
        for (int k = 0; k < 13; ++k) {
            int l = ln8 + 8 * k;
            float sv = -INFINITY;
            if (l < LL)
                sv = feat3[l] * A0 + feat3[101 + l] * A1 + feat3[202 + l] * A2
                   + Cc + pea[l] + smk[l];
            ev[k] = sv;
            mx = fmaxf(mx, sv);
        }
        #pragma unroll
        for (int o = 1; o < 8; o <<= 1) mx = fmaxf(mx, __shfl_xor(mx, o, 64));
        float sm = 0.f;
        #pragma unroll
        for (int k = 0; k < 13; ++k) {
            int l = ln8 + 8 * k;
            float e = (l < LL) ? __expf(ev[k] - mx) : 0.f;
            ev[k] = e; sm += e;
        }
        #pragma unroll
        for (int o = 1; o < 8; o <<= 1) sm += __shfl_xor(sm, o, 64);
        const float ainv = 1.f / sm;
        float c0 = 0.f, c1 = 0.f, c2 = 0.f;
        #pragma unroll
        for (int k = 0; k < 13; ++k) {
            int l = ln8 + 8 * k;                 // l <= 103
            float at = ev[k] * ainv;
            attnh[h * 104 + l] = (_Float16)at;   // zeros at 101..103
            if (l < LL) {
                c0 += at * feat3[l]; c1 += at * feat3[101 + l]; c2 += at * feat3[202 + l];
            }
        }
        #pragma unroll
        for (int o = 1; o < 8; o <<= 1) {
            c0 += __shfl_xor(c0, o, 64); c1 += __shfl_xor(c1, o, 64); c2 += __shfl_xor(c2, o, 64);
        }
        if (ln8 == 0) { coefA[h * 3 + 0] = c0; coefA[h * 3 + 1] = c1; coefA[h * 3 + 2] = c2; }
    }
    WSYNC();

    // ---- staging copy to this problem's out row (coalesced 16B stores)
    {
        float* gRow = out + (size_t)bw * Nn;
        // attn: 104 x 16B
        ((int4*)gRow)[lane] = ((const int4*)attnh)[lane];
        if (lane < 40) ((int4*)gRow)[lane + 64] = ((const int4*)attnh)[lane + 64];
        // feat f16: 38 x 16B
        if (lane < 38) {
            int c = lane;
            int wd[4];
            #pragma unroll
            for (int k2 = 0; k2 < 4; ++k2) {
                unsigned lo = f2hbits(feat3[8 * c + 2 * k2]);
                unsigned hi = f2hbits(feat3[8 * c + 2 * k2 + 1]);
                wd[k2] = (int)(lo | (hi << 16));
            }
            ((int4*)(gRow + 416))[c] = make_int4(wd[0], wd[1], wd[2], wd[3]);
        }
        // sel u16: 13 x 16B
        if (lane < 13) {
            int c = lane;
            int wd[4];
            #pragma unroll
            for (int k2 = 0; k2 < 4; ++k2) {
                unsigned lo = (unsigned)sel[8 * c + 2 * k2] & 0xffffu;
                unsigned hi = (unsigned)sel[8 * c + 2 * k2 + 1] & 0xffffu;
                wd[k2] = (int)(lo | (hi << 16));
            }
            ((int4*)(gRow + 568))[c] = make_int4(wd[0], wd[1], wd[2], wd[3]);
        }
        // coef: 6 x 16B
        if (lane < 6) ((int4*)(gRow + 620))[lane] = ((const int4*)coefA)[lane];
    }
}

// ================= Kernel B v2: 2 problems concurrent per block, LDS tables =================
#define BPB 2
__global__ __launch_bounds__(256, 2) void kernelB(
    const float* __restrict__ ws,
    float* __restrict__ out) {

    __shared__ __align__(16) _Float16 PVL[LL * 132];     // 26664 B
    __shared__ __align__(16) _Float16 GPTL[EMB * 132];   // 33792 B
    __shared__ __align__(16) float wcc[620];             // WCW[512] | cb[4] | cbpe[104]
    __shared__ __align__(16) _Float16 attnL[BPB][832];
    __shared__ __align__(16) _Float16 f3h[BPB][304];
    __shared__ __align__(16) unsigned short selL[BPB][104];
    __shared__ __align__(16) float coefL[BPB][24];
    __shared__ __align__(16) float uf[BPB][EMB];
    __shared__ float cM[BPB][4];
    __shared__ __align__(16) float rowbuf[BPB][1000];

    const int tid = threadIdx.x;
    const int sub = tid >> 7;        // which problem half-block
    const int t   = tid & 127;
    const int bid = blockIdx.x;
    const int gb  = (bid & 7) * 300 + (bid >> 3);   // 2400 = 8*300, bijective
    const int p   = gb * BPB + sub;
    float* gRow = out + (size_t)p * Nn;

    // ---- stage tables (whole block, once)
    for (int c = tid; c < 3232; c += 256) {        // PVT: 12928 halves
        int hi = c * 4;
        int l = hi >> 7, col = hi & 127;
        *(int2*)(PVL + l * 132 + col) = ((const int2*)(ws + WS_PVT))[c];
    }
    for (int c = tid; c < 3328; c += 256) {        // GPT: 13312 halves
        int hi = c * 4;
        int hd = hi / 104, col = hi - hd * 104;
        *(int2*)(GPTL + hd * 132 + col) = ((const int2*)(ws + WS_GPT))[c];
    }
    for (int c = tid; c < 155; c += 256)
        ((int4*)wcc)[c] = ((const int4*)(ws + WS_WCW))[c];

    // ---- stage this problem's data + zero rowbuf (sub-block local)
    for (int c = t; c < 161; c += 128) {
        int4 v = ((const int4*)gRow)[c];
        if (c < 104)       ((int4*)attnL[sub])[c] = v;
        else if (c < 142)  ((int4*)f3h[sub])[c - 104] = v;
        else if (c < 155)  ((int4*)selL[sub])[c - 142] = v;
        else               ((int4*)coefL[sub])[c - 155] = v;
    }
    {
        f4v z = {0.f, 0.f, 0.f, 0.f};
        for (int i = t; i < 250; i += 128) *(f4v*)(rowbuf[sub] + 4 * i) = z;
    }
    __syncthreads();

    // ---- u[hd] (each of 128 threads per sub-problem owns one hd)
    {
        int hh = t >> 4;
        const _Float16* arow = attnL[sub] + hh * 104;
        float acc = 0.f;
        #pragma unroll 4
        for (int l = 0; l < LL; ++l)
            acc += (float)arow[l] * (float)PVL[l * 132 + t];
        acc += coefL[sub][hh * 3 + 0] * ws[WS_WVI + t]
             + coefL[sub][hh * 3 + 1] * ws[WS_WVI + 128 + t]
             + coefL[sub][hh * 3 + 2] * ws[WS_WVI + 256 + t]
             + ws[WS_WVI + 384 + t];
        uf[sub][t] = acc;
    }
    __syncthreads();

    // ---- coefM (first wave of each sub-block)
    if (t < 64) {
        #pragma unroll
        for (int i = 0; i < 4; ++i) {
            float v = uf[sub][t] * wcc[i * 128 + t] + uf[sub][t + 64] * wcc[i * 128 + t + 64];
            #pragma unroll
            for (int o = 32; o > 0; o >>= 1) v += __shfl_xor(v, o, 64);
            if (t == 0) cM[sub][i] = wcc[512 + i] + v;
        }
    }
    __syncthreads();

    // ---- score2 + scatter into rowbuf
    if (t < LL) {
        float acc = 0.f;
        #pragma unroll 4
        for (int hd = 0; hd < EMB; ++hd)
            acc += uf[sub][hd] * (float)GPTL[hd * 132 + t];
        float base = (float)f3h[sub][t] * cM[sub][0] + (float)f3h[sub][101 + t] * cM[sub][1]
                   + (float)f3h[sub][202 + t] * cM[sub][2] + cM[sub][3] + wcc[516 + t];
        int n = (int)selL[sub][t] & 0xFFF;
        rowbuf[sub][n] = (base + acc) * 0.08838834764831845f;
    }
    __syncthreads();

    // ---- write the full row (coalesced, nontemporal)
    for (int c = t; c < 250; c += 128) {
        f4v v = *(const f4v*)(rowbuf[sub] + 4 * c);
        __builtin_nontemporal_store(v, (f4v*)(gRow + 4 * c));
    }
}

extern "C" void kernel_launch(void* const* d_in, const int* in_sizes, int n_in,
                              void* d_out, int out_size, void* d_ws, size_t ws_size,
                              hipStream_t stream) {
    // 0 theta, 1 dist, 2 xy, 3 norm_demand, 4 ninf_mask,
    // 5 init_w, 6 init_b, 7 cur_token, 8 Wq, 9 Wk, 10 Wv, 11 Wc_w, 12 Wc_b
    const float* dist  = (const float*)d_in[1];
    const float* xy    = (const float*)d_in[2];
    const float* ndem  = (const float*)d_in[3];
    const float* ninf  = (const float*)d_in[4];
    const float* initw = (const float*)d_in[5];
    const float* initb = (const float*)d_in[6];
    const float* cur   = (const float*)d_in[7];
    const float* Wq    = (const float*)d_in[8];
    const float* Wk    = (const float*)d_in[9];
    const float* Wv    = (const float*)d_in[10];
    const float* Wcw   = (const float*)d_in[11];
    const float* Wcb   = (const float*)d_in[12];
    float* out = (float*)d_out;
    float* ws  = (float*)d_ws;

    hipLaunchKernelGGL(setup1, dim3(56),  dim3(256), 0, stream, cur, Wq, Wk, initw, initb, Wv, ws);
    hipLaunchKernelGGL(setup2, dim3(109), dim3(256), 0, stream, Wv, Wcw, Wcb, initw, initb, ws);
    hipLaunchKernelGGL(kernelA, dim3(Bb * Ww / PPB), dim3(TPB), 0, stream,
                       dist, xy, ndem, ninf, ws, out);
    hipLaunchKernelGGL(kernelB, dim3(Bb * Ww / BPB), dim3(256), 0, stream, ws, out);
}

// Round 15
// 101.966 us; speedup vs baseline: 1.1657x; 1.1657x over previous
//
#include <hip/hip_runtime.h>
#include <math.h>

#define Bb   48
#define Ww   100
#define Nn   1000
#define EMB  128
#define Hh   8
#define LL   101     // depot + 100 neighbors
#define LOCALK 100
#define TPB  128
#define PPB  2       // problems (waves) per block

typedef _Float16 half2v __attribute__((ext_vector_type(2)));
typedef _Float16 half8v __attribute__((ext_vector_type(8)));

// ---- workspace layout (float offsets)
#define WS_A    0        // [8][128] f32  a_h = (Wk q_h)/4
#define WS_PE   1024     // [101][128] f32 pos-enc
#define WS_AC   13952    // [3][8] A_i[h] then [8] C[h]
#define WS_WVI  13984    // [4][128] f32  w_i·Wv[:,hd] (i=3 -> b)
#define WS_PEA  14496    // [8][101] f32  pe[l]·a_h
#define WS_PEH  15304    // f16 [101][128] pos-enc
#define WS_PVH  21768    // f16 [128][104] PV[hd][l] = pe[l]·Wv[:,hd], l>=101 zero
#define WS_WCT  28424    // f16 [128][128] WcwT[e][hd] = Wcw[hd][e]

// per-problem LDS arena (bytes), regions time-multiplexed:
//  select : hist4[4][260]i32 @0 (4160) , list[100]u64 @4288 (800)
//  attn   : attnh[8][112]f16 @0 (1792) , uhh[128]f16 @1792
//  out    : row[1000]f32 @0 (4000)
//  stable : sel@5088 i32[101], perm@5492 u8[100], smk@5592 f32[101],
//           feat3@5996 f32[303], mhh@7216 f16[128], coef@7472 f32[24], coefM@7568 f32[4]
#define AR_SIZE 7584

#define WSYNC() do { __builtin_amdgcn_wave_barrier(); asm volatile("" ::: "memory"); } while (0)

__device__ __forceinline__ unsigned f2key(float x) {
    unsigned u = __float_as_uint(x);
    return (u & 0x80000000u) ? ~u : (u | 0x80000000u);
}
__device__ __forceinline__ float key2f(unsigned k) {
    unsigned u = (k & 0x80000000u) ? (k & 0x7fffffffu) : ~k;
    return __uint_as_float(u);
}
__device__ __forceinline__ void dot8(float& c0, float& c1, float& c2, float& c3,
                                     half8v p, half8v a) {
    c0 = __builtin_amdgcn_fdot2(__builtin_shufflevector(p, p, 0, 1),
                                __builtin_shufflevector(a, a, 0, 1), c0, false);
    c1 = __builtin_amdgcn_fdot2(__builtin_shufflevector(p, p, 2, 3),
                                __builtin_shufflevector(a, a, 2, 3), c1, false);
    c2 = __builtin_amdgcn_fdot2(__builtin_shufflevector(p, p, 4, 5),
                                __builtin_shufflevector(a, a, 4, 5), c2, false);
    c3 = __builtin_amdgcn_fdot2(__builtin_shufflevector(p, p, 6, 7),
                                __builtin_shufflevector(a, a, 6, 7), c3, false);
}

// ---- S1: q, a, A/C (block 0); pe + WVi (blocks 1..)
__global__ void setup1(const float* __restrict__ cur, const float* __restrict__ Wq,
                       const float* __restrict__ Wk, const float* __restrict__ iw,
                       const float* __restrict__ ib, const float* __restrict__ Wv,
                       float* __restrict__ ws) {
    const int t = threadIdx.x, b = blockIdx.x;
    if (b == 0) {
        __shared__ float qs[EMB];
        __shared__ float as_[Hh * EMB];
        if (t < EMB) {
            float acc = 0.f;
            for (int e = 0; e < EMB; ++e) acc += cur[e] * Wq[e * EMB + t];
            qs[t] = acc;
        }
        __syncthreads();
        for (int i = t; i < Hh * EMB; i += 256) {
            int h = i >> 7, e = i & 127;
            float acc = 0.f;
            for (int d = 0; d < 16; ++d) acc += Wk[e * EMB + h * 16 + d] * qs[h * 16 + d];
            acc *= 0.25f;
            as_[i] = acc; ws[WS_A + i] = acc;
        }
        __syncthreads();
        if (t < 32) {
            int i = t >> 3, h = t & 7;
            const float* src = (i == 0) ? iw : (i == 1) ? iw + EMB : (i == 2) ? iw + 2 * EMB : ib;
            float acc = 0.f;
            for (int e = 0; e < EMB; ++e) acc += src[e] * as_[h * EMB + e];
            ws[WS_AC + t] = acc;
        }
    } else {
        int base = (b - 1) * 256 + t;
        const float kneg = -0.14619587891040738f;  // -ln(10000)/63
        if (base < LL * EMB) {
            int l = base >> 7, c = base & 127, ic = c & 63;
            float inv = expf((float)ic * kneg);
            float v = (float)l * inv;
            float r = (c < 64) ? sinf(v) : cosf(v);
            ws[WS_PE + base] = r;
            ((_Float16*)(ws + WS_PEH))[base] = (_Float16)r;
        } else if (base < LL * EMB + 512) {
            int j = base - LL * EMB;
            int iv = j >> 7, hd = j & 127;
            const float* src = (iv == 0) ? iw : (iv == 1) ? iw + EMB : (iv == 2) ? iw + 2 * EMB : ib;
            float acc = 0.f;
            for (int e = 0; e < EMB; ++e) acc += src[e] * Wv[e * EMB + hd];
            ws[WS_WVI + j] = acc;
        }
    }
}

// ---- S2a: PVH f16 [128][104] (pad zero) + PEA f32 [8][101]
__global__ void setup2a(const float* __restrict__ Wv, float* __restrict__ ws) {
    int idx = blockIdx.x * 256 + threadIdx.x;
    if (idx < 128 * 104) {
        int hd = idx / 104, l = idx - hd * 104;
        float acc = 0.f;
        if (l < LL) {
            const float* pr = ws + WS_PE + l * EMB;
            for (int e = 0; e < EMB; ++e) acc += pr[e] * Wv[e * EMB + hd];
        }
        ((_Float16*)(ws + WS_PVH))[idx] = (_Float16)acc;
    } else if (idx < 128 * 104 + Hh * LL) {
        int j = idx - 128 * 104;
        int h = j / LL, l = j - h * LL;
        const float* pr = ws + WS_PE + l * EMB;
        const float* ar = ws + WS_A + h * EMB;
        float acc = 0.f;
        for (int e = 0; e < EMB; ++e) acc += pr[e] * ar[e];
        ws[WS_PEA + j] = acc;
    }
}

// ---- S2b: WcwT f16 [128][128]
__global__ void setup2b(const float* __restrict__ Wcw, float* __restrict__ ws) {
    int idx = blockIdx.x * 256 + threadIdx.x;
    if (idx < 128 * 128) {
        int e = idx >> 7, hd = idx & 127;
        ((_Float16*)(ws + WS_WCT))[idx] = (_Float16)Wcw[hd * EMB + e];
    }
}

__global__ __launch_bounds__(TPB, 5) void main_kernel(
    const float* __restrict__ dist,
    const float* __restrict__ xy,
    const float* __restrict__ ndem,
    const float* __restrict__ ninf,
    const float* __restrict__ iw,
    const float* __restrict__ ib,
    const float* __restrict__ Wcb,
    const float* __restrict__ ws,
    float* __restrict__ out) {

    __shared__ __align__(16) char smem[PPB][AR_SIZE];
    const int tid  = threadIdx.x;
    const int w    = tid >> 6;
    const int lane = tid & 63;
    const int bw   = blockIdx.x * PPB + w;     // 2400 * 2 = 4800 exact

    char* A = smem[w];
    int*                hist4 = (int*)A;                      // [4][260]
    _Float16*           attnh = (_Float16*)A;                 // [8][112]
    _Float16*           uhh   = (_Float16*)(A + 1792);        // [128]
    float*              row   = (float*)A;                    // [1000]
    unsigned long long* list  = (unsigned long long*)(A + 4288);
    int*                sel   = (int*)(A + 5088);             // [101]
    unsigned char*      perm  = (unsigned char*)(A + 5492);   // [100] list-pos -> rank
    float*              smk   = (float*)(A + 5592);           // [101]
    float*              feat3 = (float*)(A + 5996);           // [303]
    _Float16*           mhh   = (_Float16*)(A + 7216);        // [128]
    float*              coef  = (float*)(A + 7472);           // [8][3]
    float*              coefM = (float*)(A + 7568);           // [4]

    const float* distRow = dist + (size_t)bw * Nn;
    const float* maskRow = ninf + (size_t)bw * Nn;
    const float* xyRow   = xy   + (size_t)bw * Nn * 2;
    const float* demRow  = ndem + (size_t)bw * Nn;

    // ---- phase 0: stream dist+mask (coalesced float4), keep mask in regs
    float dvf[16], mkf[16];
    {
        float4 dv[4], mv[4];
        #pragma unroll
        for (int c = 0; c < 4; ++c) {
            int n0 = c * 256 + lane * 4;
            if (n0 < Nn) {
                dv[c] = *(const float4*)(distRow + n0);
                mv[c] = *(const float4*)(maskRow + n0);
            } else {
                dv[c] = make_float4(0.f, 0.f, 0.f, 0.f);
                mv[c] = make_float4(0.f, 0.f, 0.f, 0.f);
            }
        }
        // zero sub-histograms while loads are in flight
        #pragma unroll
        for (int k = 0; k < 5; ++k) {
            int idx = lane + 64 * k;
            if (idx < 260) ((int4*)hist4)[idx] = make_int4(0, 0, 0, 0);
        }
        #pragma unroll
        for (int c = 0; c < 4; ++c) {
            dvf[4*c+0] = dv[c].x; dvf[4*c+1] = dv[c].y; dvf[4*c+2] = dv[c].z; dvf[4*c+3] = dv[c].w;
            mkf[4*c+0] = mv[c].x; mkf[4*c+1] = mv[c].y; mkf[4*c+2] = mv[c].z; mkf[4*c+3] = mv[c].w;
        }
    }
    // keys: node n = c*256 + lane*4 + j  (depot n==0 and pad n>=1000 excluded)
    unsigned long long rk[16];
    #pragma unroll
    for (int r = 0; r < 16; ++r) {
        int n = (r >> 2) * 256 + lane * 4 + (r & 3);
        unsigned long long kv = ~0ull;
        if (n >= 1 && n < Nn) {
            float de = dvf[r] - mkf[r];
            kv = ((unsigned long long)f2key(de) << 32) | (unsigned)n;
        }
        rk[r] = kv;
    }
    WSYNC();

    // ---- radix select (MSB-first, 4 bank-staggered sub-hists), wave-local
    unsigned long long prefix = 0;
    int shift = 56;
    int remRank = 99;
    const unsigned long long ltm = (1ull << lane) - 1ull;
    const int g0 = (lane >> 4) * 260;
    for (int round = 0; round < 8; ++round) {
        shift = 56 - 8 * round;
        #pragma unroll
        for (int r = 0; r < 16; ++r) {
            unsigned long long kv = rk[r];
            bool in = (kv != ~0ull) &&
                      (round == 0 || (kv >> (shift + 8)) == (prefix >> (shift + 8)));
            if (in) atomicAdd(&hist4[g0 + (int)((kv >> shift) & 0xffull)], 1);
        }
        WSYNC();
        int4 h0 = *(int4*)&hist4[0 * 260 + 4 * lane];
        int4 h1 = *(int4*)&hist4[1 * 260 + 4 * lane];
        int4 h2 = *(int4*)&hist4[2 * 260 + 4 * lane];
        int4 h3 = *(int4*)&hist4[3 * 260 + 4 * lane];
        int4 z = make_int4(0, 0, 0, 0);
        *(int4*)&hist4[0 * 260 + 4 * lane] = z;
        *(int4*)&hist4[1 * 260 + 4 * lane] = z;
        *(int4*)&hist4[2 * 260 + 4 * lane] = z;
        *(int4*)&hist4[3 * 260 + 4 * lane] = z;
        int cx = h0.x + h1.x + h2.x + h3.x;
        int cy = h0.y + h1.y + h2.y + h3.y;
        int cz = h0.z + h1.z + h2.z + h3.z;
        int cw = h0.w + h1.w + h2.w + h3.w;
        int s = cx + cy + cz + cw;
        int incl = s;
        #pragma unroll
        for (int o = 1; o < 64; o <<= 1) { int t = __shfl_up(incl, o, 64); if (lane >= o) incl += t; }
        int e0 = incl - s;
        int e1 = e0 + cx, e2 = e1 + cy, e3 = e2 + cz;
        int bc = -1, ec = 0, cc = 0;
        if (cx > 0 && remRank >= e0 && remRank < e1)      { bc = 4*lane+0; ec = e0; cc = cx; }
        if (cy > 0 && remRank >= e1 && remRank < e2)      { bc = 4*lane+1; ec = e1; cc = cy; }
        if (cz > 0 && remRank >= e2 && remRank < e3)      { bc = 4*lane+2; ec = e2; cc = cz; }
        if (cw > 0 && remRank >= e3 && remRank < e3 + cw) { bc = 4*lane+3; ec = e3; cc = cw; }
        unsigned long long fm = __ballot(bc >= 0);
        int srcl = __ffsll((unsigned long long)fm) - 1;
        bc = __shfl(bc, srcl, 64); ec = __shfl(ec, srcl, 64); cc = __shfl(cc, srcl, 64);
        prefix |= ((unsigned long long)(unsigned)bc) << shift;
        remRank -= ec;
        if (cc == 1) break;
    }
    // pivot key (unique match on resolved prefix)
    unsigned long long pk = 0; bool pf = false;
    #pragma unroll
    for (int r = 0; r < 16; ++r)
        if ((rk[r] >> shift) == (prefix >> shift)) { pk = rk[r]; pf = true; }
    {
        unsigned long long fm = __ballot(pf);
        int srcl = __ffsll((unsigned long long)fm) - 1;
        pk = __shfl(pk, srcl, 64);
    }
    const unsigned long long pivot = pk;

    // ---- ballot-compact the 100 keys <= pivot into list (p-order)
    int cnt_run = 0;
    #pragma unroll
    for (int r = 0; r < 16; ++r) {
        bool p = rk[r] <= pivot;
        unsigned long long m = __ballot(p);
        if (p) list[cnt_run + (int)__popcll(m & ltm)] = rk[r];
        cnt_run += (int)__popcll(m);
    }
    WSYNC();

    // ---- parallel rank: perm[p] = rank+1 ; norm max
    {
        unsigned long long kv0 = list[lane];
        const bool has1 = lane < (LOCALK - 64);
        unsigned long long kv1 = has1 ? list[lane + 64] : ~0ull;
        int r0 = 0, r1 = 0;
        #pragma unroll 4
        for (int j = 0; j < LOCALK; ++j) {
            unsigned long long lv = list[j];
            r0 += (lv < kv0);
            r1 += (lv < kv1);
        }
        float v0 = key2f((unsigned)(kv0 >> 32));
        float dvm = isinf(v0) ? 0.f : v0;
        perm[lane] = (unsigned char)(r0 + 1);
        if (has1) {
            float v1 = key2f((unsigned)(kv1 >> 32));
            perm[lane + 64] = (unsigned char)(r1 + 1);
            dvm = fmaxf(dvm, isinf(v1) ? 0.f : v1);
        }
        #pragma unroll
        for (int o = 32; o > 0; o >>= 1) dvm = fmaxf(dvm, __shfl_xor(dvm, o, 64));
        const float nmax = dvm;
        const bool  norm_on = (nmax != 0.f);
        const float nfac = nmax + 1e-6f;
        WSYNC();

        // ---- streamed feature scatter: re-derive p per key, write at rank (NO global gather)
        int crun = 0;
        #pragma unroll
        for (int half = 0; half < 2; ++half) {
            // stream xy + ndem for this half's 8 nodes (coalesced float4)
            float xs[8], ys[8], dd[8];
            #pragma unroll
            for (int cl = 0; cl < 2; ++cl) {
                int c = half * 2 + cl;
                int n0 = c * 256 + lane * 4;
                float4 a0, a1, d0;
                if (n0 < Nn) {
                    a0 = *(const float4*)(xyRow + 2 * n0);
                    a1 = *(const float4*)(xyRow + 2 * n0 + 4);
                    d0 = *(const float4*)(demRow + n0);
                } else {
                    a0 = a1 = d0 = make_float4(0.f, 0.f, 0.f, 0.f);
                }
                xs[4*cl+0] = a0.x; ys[4*cl+0] = a0.y;
                xs[4*cl+1] = a0.z; ys[4*cl+1] = a0.w;
                xs[4*cl+2] = a1.x; ys[4*cl+2] = a1.y;
                xs[4*cl+3] = a1.z; ys[4*cl+3] = a1.w;
                dd[4*cl+0] = d0.x; dd[4*cl+1] = d0.y; dd[4*cl+2] = d0.z; dd[4*cl+3] = d0.w;
            }
            #pragma unroll
            for (int q = 0; q < 8; ++q) {
                int r = half * 8 + q;
                unsigned long long kv = rk[r];
                bool p = kv <= pivot;
                unsigned long long m = __ballot(p);
                int pos = crun + (int)__popcll(m & ltm);
                crun += (int)__popcll(m);
                if (p) {
                    int rnk = perm[pos];
                    float val = key2f((unsigned)(kv >> 32));
                    bool infm = isinf(val);
                    float fx = infm ? 0.f : xs[q];
                    float fy = infm ? 0.f : ys[q];
                    float fd = infm ? 0.f : dd[q];
                    if (norm_on) { fx /= nfac; fy /= nfac; }
                    int n = (int)(kv & 0xffffffu);
                    feat3[rnk] = fx; feat3[101 + rnk] = fy; feat3[202 + rnk] = fd;
                    smk[rnk] = mkf[r];
                    sel[rnk] = n | (infm ? 0x40000000 : 0);
                }
            }
        }
        if (lane == 0) {   // depot: rank 0, node 0, inf flag
            feat3[0] = 0.f; feat3[101] = 0.f; feat3[202] = 0.f;
            smk[0] = mkf[0];
            sel[0] = 0x40000000;
        }
    }
    WSYNC();

    // ---- fused scores + softmax + coef: 8 lanes per head
    const int h = lane >> 3, ln8 = lane & 7;
    {
        const float A0 = ws[WS_AC + h], A1 = ws[WS_AC + 8 + h];
        const float A2 = ws[WS_AC + 16 + h], Cc = ws[WS_AC + 24 + h];
        const float* pea = ws + WS_PEA + h * LL;
        float ev[14];
        float mx = -INFINITY;
        #pragma unroll
        for (int k = 0; k < 14; ++k) {
            int l = ln8 + 8 * k;
            float sv = -INFINITY;
            if (l < LL)
                sv = feat3[l] * A0 + feat3[101 + l] * A1 + feat3[202 + l] * A2
                   + Cc + pea[l] + smk[l];
            ev[k] = sv;
            mx = fmaxf(mx, sv);
        }
        #pragma unroll
        for (int o = 1; o < 8; o <<= 1) mx = fmaxf(mx, __shfl_xor(mx, o, 64));
        float sm = 0.f;
        #pragma unroll
        for (int k = 0; k < 14; ++k) {
            int l = ln8 + 8 * k;
            float e = (l < LL) ? __expf(ev[k] - mx) : 0.f;
            ev[k] = e; sm += e;
        }
        #pragma unroll
        for (int o = 1; o < 8; o <<= 1) sm += __shfl_xor(sm, o, 64);
        const float ainv = 1.f / sm;
        #pragma unroll
        for (int k = 0; k < 14; ++k) {
            int l = ln8 + 8 * k;                 // l <= 111 always
            attnh[h * 112 + l] = (_Float16)(ev[k] * ainv);
        }
        float c0 = 0.f, c1 = 0.f, c2 = 0.f;
        #pragma unroll
        for (int k = 0; k < 13; ++k) {
            int l = ln8 + 8 * k;
            if (l < LL) {
                float at = ev[k] * ainv;
                c0 += at * feat3[l]; c1 += at * feat3[101 + l]; c2 += at * feat3[202 + l];
            }
        }
        #pragma unroll
        for (int o = 1; o < 8; o <<= 1) {
            c0 += __shfl_xor(c0, o, 64); c1 += __shfl_xor(c1, o, 64); c2 += __shfl_xor(c2, o, 64);
        }
        if (ln8 == 0) { coef[h * 3 + 0] = c0; coef[h * 3 + 1] = c1; coef[h * 3 + 2] = c2; }
    }
    WSYNC();

    // ---- u[hd] = attn[h] . PV[hd] + rank-3 corrections
    #pragma unroll
    for (int t = 0; t < 2; ++t) {
        int hd = lane + 64 * t;
        int hh = hd >> 4;
        const half8v* pv = (const half8v*)((const _Float16*)(ws + WS_PVH) + hd * 104);
        const half8v* at = (const half8v*)(attnh + hh * 112);
        float d0 = 0.f, d1 = 0.f, d2 = 0.f, d3 = 0.f;
        #pragma unroll
        for (int j = 0; j < 13; ++j) dot8(d0, d1, d2, d3, pv[j], at[j]);
        float u = (d0 + d1) + (d2 + d3)
                + coef[hh * 3 + 0] * ws[WS_WVI + hd]
                + coef[hh * 3 + 1] * ws[WS_WVI + 128 + hd]
                + coef[hh * 3 + 2] * ws[WS_WVI + 256 + hd]
                + ws[WS_WVI + 384 + hd];
        uhh[hd] = (_Float16)u;
    }
    WSYNC();

    // ---- mh[e] = Wcb[e] + u . WcwT[e]
    #pragma unroll
    for (int t = 0; t < 2; ++t) {
        int e = lane + 64 * t;
        const half8v* wr = (const half8v*)((const _Float16*)(ws + WS_WCT) + e * 128);
        const half8v* ur = (const half8v*)uhh;
        float d0 = 0.f, d1 = 0.f, d2 = 0.f, d3 = 0.f;
        #pragma unroll
        for (int j = 0; j < 16; ++j) dot8(d0, d1, d2, d3, wr[j], ur[j]);
        mhh[e] = (_Float16)(Wcb[e] + (d0 + d1) + (d2 + d3));
    }
    WSYNC();

    // ---- coefM[g] = mh . {w0,w1,w2,b}   (16 lanes per g)
    {
        int g = lane & 3;
        const float* src = (g == 0) ? iw : (g == 1) ? iw + EMB : (g == 2) ? iw + 2 * EMB : ib;
        float v = 0.f;
        #pragma unroll
        for (int j = 0; j < 8; ++j) {
            int e = (lane >> 2) + 16 * j;
            v += (float)mhh[e] * src[e];
        }
        v += __shfl_xor(v, 4, 64); v += __shfl_xor(v, 8, 64);
        v += __shfl_xor(v, 16, 64); v += __shfl_xor(v, 32, 64);
        if (lane < 4) coefM[lane] = v;
    }
    // zero LDS row (attnh/uhh/hist/list all dead now)
    {
        float4 z = make_float4(0.f, 0.f, 0.f, 0.f);
        ((float4*)row)[lane] = z;
        ((float4*)row)[lane + 64] = z;
        ((float4*)row)[lane + 128] = z;
        if (lane < 58) ((float4*)row)[lane + 192] = z;
    }
    WSYNC();

    // ---- score2[l] = (base + mh.pe[l]) / sqrt(128); scatter into LDS row
    auto score2 = [&](int t) {
        float base = feat3[t] * coefM[0] + feat3[101 + t] * coefM[1]
                   + feat3[202 + t] * coefM[2] + coefM[3];
        const half8v* pr = (const half8v*)((const _Float16*)(ws + WS_PEH) + t * 128);
        const half8v* mr = (const half8v*)mhh;
        float d0 = 0.f, d1 = 0.f, d2 = 0.f, d3 = 0.f;
        #pragma unroll
        for (int j = 0; j < 16; ++j) dot8(d0, d1, d2, d3, pr[j], mr[j]);
        row[sel[t] & 0xffffff] = (base + (d0 + d1) + (d2 + d3)) * 0.08838834764831845f;
    };
    score2(lane);
    if (lane < LL - 64) score2(lane + 64);
    WSYNC();

    // ---- stream the row out coalesced
    float* outRow = out + (size_t)bw * Nn;
    ((float4*)outRow)[lane]       = ((float4*)row)[lane];
    ((float4*)outRow)[lane + 64]  = ((float4*)row)[lane + 64];
    ((float4*)outRow)[lane + 128] = ((float4*)row)[lane + 128];
    if (lane < 58) ((float4*)outRow)[lane + 192] = ((float4*)row)[lane + 192];
}

extern "C" void kernel_launch(void* const* d_in, const int* in_sizes, int n_in,
                              void* d_out, int out_size, void* d_ws, size_t ws_size,
                              hipStream_t stream) {
    // 0 theta, 1 dist, 2 xy, 3 norm_demand, 4 ninf_mask,
    // 5 init_w, 6 init_b, 7 cur_token, 8 Wq, 9 Wk, 10 Wv, 11 Wc_w, 12 Wc_b
    const float* dist  = (const float*)d_in[1];
    const float* xy    = (const float*)d_in[2];
    const float* ndem  = (const float*)d_in[3];
    const float* ninf  = (const float*)d_in[4];
    const float* initw = (const float*)d_in[5];
    const float* initb = (const float*)d_in[6];
    const float* cur   = (const float*)d_in[7];
    const float* Wq    = (const float*)d_in[8];
    const float* Wk    = (const float*)d_in[9];
    const float* Wv    = (const float*)d_in[10];
    const float* Wcw   = (const float*)d_in[11];
    const float* Wcb   = (const float*)d_in[12];
    float* out = (float*)d_out;
    float* ws  = (float*)d_ws;

    hipLaunchKernelGGL(setup1,  dim3(56), dim3(256), 0, stream, cur, Wq, Wk, initw, initb, Wv, ws);
    hipLaunchKernelGGL(setup2a, dim3(56), dim3(256), 0, stream, Wv, ws);
    hipLaunchKernelGGL(setup2b, dim3(64), dim3(256), 0, stream, Wcw, ws);
    hipLaunchKernelGGL(main_kernel, dim3(Bb * Ww / PPB), dim3(TPB), 0, stream,
                       dist, xy, ndem, ninf, initw, initb, Wcb, ws, out);
}